// Round 5
// baseline (28125.476 us; speedup 1.0000x reference)
//
#include <hip/hip_runtime.h>

#define LSTM_B   4096
#define LSTM_H   1024
#define LSTM_IN  512
#define LSTM_OUT 512

typedef unsigned long long u64;
typedef unsigned int u32;
typedef float f32x2 __attribute__((ext_vector_type(2)));

__device__ __forceinline__ u64 aload(u64* p) {
  return __hip_atomic_load(p, __ATOMIC_RELAXED, __HIP_MEMORY_SCOPE_AGENT);
}
__device__ __forceinline__ void astore(u64* p, u64 v) {
  __hip_atomic_store(p, v, __ATOMIC_RELAXED, __HIP_MEMORY_SCOPE_AGENT);
}
__device__ __forceinline__ u64 packft(float f, u32 tag) {
  return ((u64)tag << 32) | (u64)__float_as_uint(f);
}
__device__ __forceinline__ float dot4f(float4 a, float4 b) {
  return fmaf(a.x, b.x, fmaf(a.y, b.y, fmaf(a.z, b.z, a.w * b.w)));
}
// fast activations: v_exp_f32 + v_rcp_f32. |rel err| ~1e-6, bounded outputs.
__device__ __forceinline__ float fsig(float x) {
  return __builtin_amdgcn_rcpf(1.0f + __expf(-x));
}
__device__ __forceinline__ float ftanh(float x) {
  return 1.0f - 2.0f * __builtin_amdgcn_rcpf(1.0f + __expf(2.0f * x));
}
// packed 2xf32 fma -> v_pk_fma_f32 on CDNA (halves FMA issue count)
__device__ __forceinline__ f32x2 pkfma(f32x2 a, f32x2 b, f32x2 c) {
  return __builtin_elementwise_fma(a, b, c);
}
__device__ __forceinline__ f32x2 mkpair(float a, float b) {
  f32x2 r; r.x = a; r.y = b; return r;
}

// Pin a loaded value into a register. asm volatile is opaque: the compiler can
// neither rematerialize the original global load inside the loop nor sink it.
__device__ __forceinline__ float pin1(float v) {
  float r;
  asm volatile("v_mov_b32 %0, %1" : "=v"(r) : "v"(v));
  return r;
}

// wave64 sum on the VALU pipe via DPP. Result valid in lane 63 ONLY.
template <int CTRL, int RM>
__device__ __forceinline__ float dpp_add(float x) {
  return x + __int_as_float(
      __builtin_amdgcn_update_dpp(0, __float_as_int(x), CTRL, RM, 0xf, true));
}
__device__ __forceinline__ float wsum63(float x) {
  x = dpp_add<0x111, 0xf>(x);   // row_shr:1
  x = dpp_add<0x112, 0xf>(x);   // row_shr:2
  x = dpp_add<0x114, 0xf>(x);   // row_shr:4
  x = dpp_add<0x118, 0xf>(x);   // row_shr:8  -> lanes 15/31/47/63 = row sums
  x = dpp_add<0x142, 0xa>(x);   // row_bcast:15 -> lane31, lane63 partials
  x = dpp_add<0x143, 0xc>(x);   // row_bcast:31 -> lane63 = total
  return x;
}

// LDS-only barrier: the default __syncthreads() emits s_waitcnt vmcnt(0)
// which would drain our discarded in-flight poll loads (~RTT/2 stall).
// LDS ordering only needs lgkmcnt(0) + s_barrier.
__device__ __forceinline__ void block_sync_lds() {
  asm volatile("s_waitcnt lgkmcnt(0)" ::: "memory");
  __builtin_amdgcn_s_barrier();
}

// Depth-2 pipelined tag-poll of one 32B chunk (4 tagged u64 slots).
// Two banks of 4 loads leapfrog: check the older bank while the newer is in
// flight -> sampling period ~RTT/2 instead of RTT+sleep. sched_barrier pins
// "issue next bank BEFORE checking previous" so the compiler can't collapse
// the pipeline into serial round-trips.
__device__ __forceinline__ float4 poll_chunk(u64* p, u32 tt) {
  u64 a0, a1, a2, a3, b0, b1, b2, b3, r0, r1, r2, r3;
  a0 = aload(p); a1 = aload(p + 1); a2 = aload(p + 2); a3 = aload(p + 3);
  b0 = aload(p); b1 = aload(p + 1); b2 = aload(p + 2); b3 = aload(p + 3);
  __builtin_amdgcn_sched_barrier(0);
  for (;;) {
    bool hit = ((u32)(a0 >> 32) == tt) & ((u32)(a1 >> 32) == tt) &
               ((u32)(a2 >> 32) == tt) & ((u32)(a3 >> 32) == tt);
    if (__all(hit)) { r0 = a0; r1 = a1; r2 = a2; r3 = a3; break; }
    a0 = aload(p); a1 = aload(p + 1); a2 = aload(p + 2); a3 = aload(p + 3);
    __builtin_amdgcn_sched_barrier(0);
    __builtin_amdgcn_s_sleep(1);
    hit = ((u32)(b0 >> 32) == tt) & ((u32)(b1 >> 32) == tt) &
          ((u32)(b2 >> 32) == tt) & ((u32)(b3 >> 32) == tt);
    if (__all(hit)) { r0 = b0; r1 = b1; r2 = b2; r3 = b3; break; }
    b0 = aload(p); b1 = aload(p + 1); b2 = aload(p + 2); b3 = aload(p + 3);
    __builtin_amdgcn_sched_barrier(0);
    __builtin_amdgcn_s_sleep(1);
  }
  float4 hv;
  hv.x = __uint_as_float((u32)r0);
  hv.y = __uint_as_float((u32)r1);
  hv.z = __uint_as_float((u32)r2);
  hv.w = __uint_as_float((u32)r3);
  return hv;
}

// ---------------- transpose fc_w [512,1024] -> fcwT [1024,512] ----------------
__global__ void k_transpose(const float* __restrict__ w, float* __restrict__ wT) {
  int idx = blockIdx.x * 256 + threadIdx.x;   // 512*1024 total
  int k = idx >> 9;
  int o = idx & 511;
  wT[idx] = w[o * 1024 + k];
}

// ---------------- persistent recurrent kernel ----------------
// 256 blocks x 512 threads (8 waves, 1 block/CU, 2 waves/SIMD).
// Blocks 0..127: layer-0, block bx owns units 8bx..8bx+7 (one per wave).
// Blocks 128..255: layer-1, same mapping. Tagged u64 slots; contiguous 32B
// chunk per polling thread; depth-2 pipelined polls; LDS stage + one raw
// barrier per step; packed-f32 dots; DPP reduce; lane-63 store.
__global__ __launch_bounds__(512)
__attribute__((amdgpu_waves_per_eu(2, 2)))
void k_recur(
    const float* __restrict__ x,
    const float* __restrict__ Whh0, const float* __restrict__ Wih0,
    const float* __restrict__ bih0, const float* __restrict__ bhh0,
    const float* __restrict__ Wih1, const float* __restrict__ Whh1,
    const float* __restrict__ bih1, const float* __restrict__ bhh1,
    const float* __restrict__ h0in, const float* __restrict__ c0in,
    u64* __restrict__ h0buf, u64* __restrict__ h1buf)
{
  __shared__ float h0s[2][LSTM_H];
  __shared__ float h1s[2][LSTM_H];   // layer-1 blocks only

  const int tid = threadIdx.x;       // 0..511
  const int w = tid >> 6, l = tid & 63;
  const bool lay1 = (blockIdx.x >= 128);
  const int bx = lay1 ? (int)blockIdx.x - 128 : (int)blockIdx.x;
  const int hd = 8 * bx + w;         // this wave's output unit

  if (!lay1) {
    // ===================== layer-0 blocks =====================
    f32x2 Wh2[4][4][2];              // Whh0 rows, packed pairs (cols q*256+4l..)
    f32x2 Wx2[4][4];                 // Wih0, cols 128m+2l..
#pragma unroll
    for (int g = 0; g < 4; ++g) {
#pragma unroll
      for (int q = 0; q < 4; ++q) {
        float4 u = *(const float4*)&Whh0[(size_t)(g * 1024 + hd) * 1024 + q * 256 + 4 * l];
        Wh2[g][q][0] = mkpair(pin1(u.x), pin1(u.y));
        Wh2[g][q][1] = mkpair(pin1(u.z), pin1(u.w));
      }
#pragma unroll
      for (int m = 0; m < 4; ++m) {
        float2 u = *(const float2*)&Wih0[(size_t)(g * 1024 + hd) * 512 + 128 * m + 2 * l];
        Wx2[g][m] = mkpair(pin1(u.x), pin1(u.y));
      }
    }
    float bsum[4];
#pragma unroll
    for (int g = 0; g < 4; ++g) bsum[g] = bih0[g * 1024 + hd] + bhh0[g * 1024 + hd];
    float c = c0in[hd];

    h0s[1][tid]       = h0in[tid];
    h0s[1][tid + 512] = h0in[tid + 512];
    __syncthreads();

    // step 0: f(h0_init, x[0]) -> h0buf slot 0, tag 0
    {
      f32x2 A0 = {0.f, 0.f}, A1 = {0.f, 0.f}, A2 = {0.f, 0.f}, A3 = {0.f, 0.f};
#pragma unroll
      for (int m = 0; m < 4; ++m) {
        f32x2 xv = *(const f32x2*)&x[128 * m + 2 * l];
        A0 = pkfma(Wx2[0][m], xv, A0);
        A1 = pkfma(Wx2[1][m], xv, A1);
        A2 = pkfma(Wx2[2][m], xv, A2);
        A3 = pkfma(Wx2[3][m], xv, A3);
      }
#pragma unroll
      for (int q = 0; q < 4; ++q) {
        float4 hq = *(const float4*)&h0s[1][q * 256 + 4 * l];
        f32x2 h01 = mkpair(hq.x, hq.y), h23 = mkpair(hq.z, hq.w);
        A0 = pkfma(Wh2[0][q][0], h01, A0); A0 = pkfma(Wh2[0][q][1], h23, A0);
        A1 = pkfma(Wh2[1][q][0], h01, A1); A1 = pkfma(Wh2[1][q][1], h23, A1);
        A2 = pkfma(Wh2[2][q][0], h01, A2); A2 = pkfma(Wh2[2][q][1], h23, A2);
        A3 = pkfma(Wh2[3][q][0], h01, A3); A3 = pkfma(Wh2[3][q][1], h23, A3);
      }
      float a0 = wsum63(A0.x + A0.y), a1 = wsum63(A1.x + A1.y);
      float a2 = wsum63(A2.x + A2.y), a3 = wsum63(A3.x + A3.y);
      c = fsig(a1 + bsum[1]) * c + fsig(a0 + bsum[0]) * ftanh(a2 + bsum[2]);
      float hn = fsig(a3 + bsum[3]) * ftanh(c);
      if (l == 63) astore(&h0buf[hd], packft(hn, 0u));   // lane 63 holds real sums
    }

    u64* p = &h0buf[4 * tid];        // valid for tid<256 (chunk units 4tid..+3)
#pragma unroll 1
    for (int t = 0; t < LSTM_B - 1; ++t, p += 1024) {
      const int buf = t & 1;
      const u32 tt = (u32)t;
      // x(t+1) partial gates: off the critical chain, overlaps peers' flight.
      f32x2 A0 = {0.f, 0.f}, A1 = {0.f, 0.f}, A2 = {0.f, 0.f}, A3 = {0.f, 0.f};
#pragma unroll
      for (int m = 0; m < 4; ++m) {
        f32x2 xv = *(const f32x2*)&x[(size_t)(t + 1) * 512 + 128 * m + 2 * l];
        A0 = pkfma(Wx2[0][m], xv, A0);
        A1 = pkfma(Wx2[1][m], xv, A1);
        A2 = pkfma(Wx2[2][m], xv, A2);
        A3 = pkfma(Wx2[3][m], xv, A3);
      }
      // waves 0-3 poll h0(t) chunks; waves 4-7 go straight to the barrier
      if (tid < 256) {
        float4 hv = poll_chunk(p, tt);
        *(float4*)&h0s[buf][4 * tid] = hv;
      }
      block_sync_lds();
#pragma unroll
      for (int q = 0; q < 4; ++q) {
        float4 hq = *(const float4*)&h0s[buf][q * 256 + 4 * l];
        f32x2 h01 = mkpair(hq.x, hq.y), h23 = mkpair(hq.z, hq.w);
        A0 = pkfma(Wh2[0][q][0], h01, A0); A0 = pkfma(Wh2[0][q][1], h23, A0);
        A1 = pkfma(Wh2[1][q][0], h01, A1); A1 = pkfma(Wh2[1][q][1], h23, A1);
        A2 = pkfma(Wh2[2][q][0], h01, A2); A2 = pkfma(Wh2[2][q][1], h23, A2);
        A3 = pkfma(Wh2[3][q][0], h01, A3); A3 = pkfma(Wh2[3][q][1], h23, A3);
      }
      float a0 = wsum63(A0.x + A0.y), a1 = wsum63(A1.x + A1.y);
      float a2 = wsum63(A2.x + A2.y), a3 = wsum63(A3.x + A3.y);
      c = fsig(a1 + bsum[1]) * c + fsig(a0 + bsum[0]) * ftanh(a2 + bsum[2]);
      float hn = fsig(a3 + bsum[3]) * ftanh(c);
      if (l == 63) astore(&h0buf[(size_t)(t + 1) * 1024 + hd], packft(hn, tt + 1));
    }
  } else {
    // ===================== layer-1 blocks =====================
    f32x2 Wi2[4][4][2], Whh2[4][4][2];
#pragma unroll
    for (int g = 0; g < 4; ++g)
#pragma unroll
      for (int q = 0; q < 4; ++q) {
        float4 u = *(const float4*)&Wih1[(size_t)(g * 1024 + hd) * 1024 + q * 256 + 4 * l];
        Wi2[g][q][0] = mkpair(pin1(u.x), pin1(u.y));
        Wi2[g][q][1] = mkpair(pin1(u.z), pin1(u.w));
        float4 v = *(const float4*)&Whh1[(size_t)(g * 1024 + hd) * 1024 + q * 256 + 4 * l];
        Whh2[g][q][0] = mkpair(pin1(v.x), pin1(v.y));
        Whh2[g][q][1] = mkpair(pin1(v.z), pin1(v.w));
      }
    float bsum[4];
#pragma unroll
    for (int g = 0; g < 4; ++g) bsum[g] = bih1[g * 1024 + hd] + bhh1[g * 1024 + hd];
    float c = c0in[1024 + hd];
    if (l == 63) astore(&h1buf[hd], packft(h0in[1024 + hd], 0u));  // seed h1(init)

    // split polling: threads 0-255 own h0 chunk 4*tid; 256-511 own h1 chunk
    u64* p = (tid < 256) ? &h0buf[4 * tid] : &h1buf[4 * (tid - 256)];
    const int ci = (tid < 256) ? 4 * tid : 4 * (tid - 256);
    const bool ish0 = (tid < 256);
#pragma unroll 1
    for (int t = 0; t < LSTM_B; ++t, p += 1024) {
      const int buf = t & 1;
      const u32 tt = (u32)t;
      {
        float4 hv = poll_chunk(p, tt);
        if (ish0) *(float4*)&h0s[buf][ci] = hv;
        else      *(float4*)&h1s[buf][ci] = hv;
      }
      block_sync_lds();
      f32x2 A0 = {0.f, 0.f}, A1 = {0.f, 0.f}, A2 = {0.f, 0.f}, A3 = {0.f, 0.f};
#pragma unroll
      for (int q = 0; q < 4; ++q) {
        float4 hq = *(const float4*)&h0s[buf][q * 256 + 4 * l];
        f32x2 h01 = mkpair(hq.x, hq.y), h23 = mkpair(hq.z, hq.w);
        A0 = pkfma(Wi2[0][q][0], h01, A0); A0 = pkfma(Wi2[0][q][1], h23, A0);
        A1 = pkfma(Wi2[1][q][0], h01, A1); A1 = pkfma(Wi2[1][q][1], h23, A1);
        A2 = pkfma(Wi2[2][q][0], h01, A2); A2 = pkfma(Wi2[2][q][1], h23, A2);
        A3 = pkfma(Wi2[3][q][0], h01, A3); A3 = pkfma(Wi2[3][q][1], h23, A3);
      }
#pragma unroll
      for (int q = 0; q < 4; ++q) {
        float4 hq = *(const float4*)&h1s[buf][q * 256 + 4 * l];
        f32x2 h01 = mkpair(hq.x, hq.y), h23 = mkpair(hq.z, hq.w);
        A0 = pkfma(Whh2[0][q][0], h01, A0); A0 = pkfma(Whh2[0][q][1], h23, A0);
        A1 = pkfma(Whh2[1][q][0], h01, A1); A1 = pkfma(Whh2[1][q][1], h23, A1);
        A2 = pkfma(Whh2[2][q][0], h01, A2); A2 = pkfma(Whh2[2][q][1], h23, A2);
        A3 = pkfma(Whh2[3][q][0], h01, A3); A3 = pkfma(Whh2[3][q][1], h23, A3);
      }
      float a0 = wsum63(A0.x + A0.y), a1 = wsum63(A1.x + A1.y);
      float a2 = wsum63(A2.x + A2.y), a3 = wsum63(A3.x + A3.y);
      c = fsig(a1 + bsum[1]) * c + fsig(a0 + bsum[0]) * ftanh(a2 + bsum[2]);
      float hn = fsig(a3 + bsum[3]) * ftanh(c);
      if (l == 63) astore(&h1buf[(size_t)(t + 1) * 1024 + hd], packft(hn, tt + 1));
    }
  }
}

// ---------------- FC + softmax: 16 timesteps per block ----------------
__global__ __launch_bounds__(256) void k_fc(u64* __restrict__ h1buf,
                                            const float* __restrict__ fcwT,
                                            const float* __restrict__ fcb,
                                            float* __restrict__ out) {
  __shared__ float smem[16 * 1024];
  const int tid = threadIdx.x;
  const int t0 = blockIdx.x * 16;

  for (int i = 0; i < 64; ++i) {
    int e = tid + 256 * i;
    int tt = e >> 10, k = e & 1023;
    u64 v = aload(&h1buf[(size_t)(t0 + tt + 1) * 1024 + k]);
    smem[e] = __uint_as_float((u32)v);
  }
  __syncthreads();

  float acc0[16], acc1[16];
#pragma unroll
  for (int tt = 0; tt < 16; ++tt) { acc0[tt] = 0.f; acc1[tt] = 0.f; }

  for (int k0 = 0; k0 < 1024; k0 += 4) {
    float4 w0v, w1v;
    w0v.x = fcwT[(k0 + 0) * 512 + tid];       w1v.x = fcwT[(k0 + 0) * 512 + 256 + tid];
    w0v.y = fcwT[(k0 + 1) * 512 + tid];       w1v.y = fcwT[(k0 + 1) * 512 + 256 + tid];
    w0v.z = fcwT[(k0 + 2) * 512 + tid];       w1v.z = fcwT[(k0 + 2) * 512 + 256 + tid];
    w0v.w = fcwT[(k0 + 3) * 512 + tid];       w1v.w = fcwT[(k0 + 3) * 512 + 256 + tid];
    float4 hv[16];
#pragma unroll
    for (int tt = 0; tt < 16; ++tt) hv[tt] = *(const float4*)&smem[tt * 1024 + k0];
#pragma unroll
    for (int tt = 0; tt < 16; ++tt) {
      acc0[tt] += dot4f(w0v, hv[tt]);
      acc1[tt] += dot4f(w1v, hv[tt]);
    }
  }
  float bb0 = fcb[tid], bb1 = fcb[tid + 256];
  __syncthreads();  // done reading h1 tile; alias smem as logits [16][512]
#pragma unroll
  for (int tt = 0; tt < 16; ++tt) {
    smem[tt * 512 + tid] = acc0[tt] + bb0;
    smem[tt * 512 + 256 + tid] = acc1[tt] + bb1;
  }
  __syncthreads();

  const int wv = tid >> 6, l = tid & 63;
  for (int r = 0; r < 4; ++r) {
    int tt = wv * 4 + r;
    float v[8];
    float mx = -3.4e38f;
#pragma unroll
    for (int m = 0; m < 8; ++m) { v[m] = smem[tt * 512 + m * 64 + l]; mx = fmaxf(mx, v[m]); }
#pragma unroll
    for (int s = 1; s < 64; s <<= 1) mx = fmaxf(mx, __shfl_xor(mx, s, 64));
    float sum = 0.f;
#pragma unroll
    for (int m = 0; m < 8; ++m) { v[m] = expf(v[m] - mx); sum += v[m]; }
#pragma unroll
    for (int s = 1; s < 64; s <<= 1) sum += __shfl_xor(sum, s, 64);
    float inv = 1.0f / sum;
#pragma unroll
    for (int m = 0; m < 8; ++m) out[(size_t)(t0 + tt) * 512 + m * 64 + l] = v[m] * inv;
  }
}

extern "C" void kernel_launch(void* const* d_in, const int* in_sizes, int n_in,
                              void* d_out, int out_size, void* d_ws, size_t ws_size,
                              hipStream_t stream) {
  const float* x    = (const float*)d_in[0];
  const float* Wih0 = (const float*)d_in[1];
  const float* Whh0 = (const float*)d_in[2];
  const float* bih0 = (const float*)d_in[3];
  const float* bhh0 = (const float*)d_in[4];
  const float* Wih1 = (const float*)d_in[5];
  const float* Whh1 = (const float*)d_in[6];
  const float* bih1 = (const float*)d_in[7];
  const float* bhh1 = (const float*)d_in[8];
  const float* h0in = (const float*)d_in[9];
  const float* c0in = (const float*)d_in[10];
  const float* fcw  = (const float*)d_in[11];
  const float* fcb  = (const float*)d_in[12];
  float* out = (float*)d_out;

  // workspace: h0buf (B slots) | h1buf (B+1 slots) | fcwT  -> ~69 MB
  u64* h0buf = (u64*)d_ws;
  u64* h1buf = h0buf + (size_t)LSTM_B * 1024;
  float* fcwT = (float*)(h1buf + (size_t)(LSTM_B + 1) * 1024);

  hipLaunchKernelGGL(k_transpose, dim3((512 * 1024) / 256), dim3(256), 0, stream, fcw, fcwT);
  hipLaunchKernelGGL(k_recur, dim3(256), dim3(512), 0, stream,
                     x, Whh0, Wih0, bih0, bhh0, Wih1, Whh1, bih1, bhh1,
                     h0in, c0in, h0buf, h1buf);
  hipLaunchKernelGGL(k_fc, dim3(LSTM_B / 16), dim3(256), 0, stream, h1buf, fcwT, fcb, out);
}

// Round 6
// 10158.486 us; speedup vs baseline: 2.7687x; 2.7687x over previous
//
#include <hip/hip_runtime.h>

#define LSTM_B   4096
#define LSTM_H   1024
#define LSTM_IN  512
#define LSTM_OUT 512

typedef unsigned long long u64;
typedef unsigned int u32;
typedef float f32x2 __attribute__((ext_vector_type(2)));

__device__ __forceinline__ u64 aload(u64* p) {
  return __hip_atomic_load(p, __ATOMIC_RELAXED, __HIP_MEMORY_SCOPE_AGENT);
}
__device__ __forceinline__ void astore(u64* p, u64 v) {
  __hip_atomic_store(p, v, __ATOMIC_RELAXED, __HIP_MEMORY_SCOPE_AGENT);
}
__device__ __forceinline__ u64 packft(float f, u32 tag) {
  return ((u64)tag << 32) | (u64)__float_as_uint(f);
}
__device__ __forceinline__ float dot4f(float4 a, float4 b) {
  return fmaf(a.x, b.x, fmaf(a.y, b.y, fmaf(a.z, b.z, a.w * b.w)));
}
// fast activations: v_exp_f32 + v_rcp_f32. |rel err| ~1e-6, bounded outputs.
__device__ __forceinline__ float fsig(float x) {
  return __builtin_amdgcn_rcpf(1.0f + __expf(-x));
}
__device__ __forceinline__ float ftanh(float x) {
  return 1.0f - 2.0f * __builtin_amdgcn_rcpf(1.0f + __expf(2.0f * x));
}
// Force the just-issued critical store out of the WC buffer before moving on.
// Round-5 lesson: WITHOUT this the 8B lane-63 store lingers (the wave issues
// only loads afterwards; nothing flushes it) -> every consumer's detect slips,
// poll traffic triples (FETCH 387MB->1GB), dur 9.6->28ms. Keep it.
__device__ __forceinline__ void drain_vmem() {
  asm volatile("s_waitcnt vmcnt(0)" ::: "memory");
}
// packed 2xf32 fma -> v_pk_fma_f32 on CDNA (halves FMA issue count)
__device__ __forceinline__ f32x2 pkfma(f32x2 a, f32x2 b, f32x2 c) {
  return __builtin_elementwise_fma(a, b, c);
}
__device__ __forceinline__ f32x2 mkpair(float a, float b) {
  f32x2 r; r.x = a; r.y = b; return r;
}

// Pin a loaded value into a register. asm volatile is opaque: the compiler can
// neither rematerialize the original global load inside the loop nor sink it.
__device__ __forceinline__ float pin1(float v) {
  float r;
  asm volatile("v_mov_b32 %0, %1" : "=v"(r) : "v"(v));
  return r;
}

// wave64 sum on the VALU pipe via DPP. Result valid in lane 63 ONLY.
template <int CTRL, int RM>
__device__ __forceinline__ float dpp_add(float x) {
  return x + __int_as_float(
      __builtin_amdgcn_update_dpp(0, __float_as_int(x), CTRL, RM, 0xf, true));
}
__device__ __forceinline__ float wsum63(float x) {
  x = dpp_add<0x111, 0xf>(x);   // row_shr:1
  x = dpp_add<0x112, 0xf>(x);   // row_shr:2
  x = dpp_add<0x114, 0xf>(x);   // row_shr:4
  x = dpp_add<0x118, 0xf>(x);   // row_shr:8  -> lanes 15/31/47/63 = row sums
  x = dpp_add<0x142, 0xa>(x);   // row_bcast:15 -> lane31, lane63 partials
  x = dpp_add<0x143, 0xc>(x);   // row_bcast:31 -> lane63 = total
  return x;
}

// Serial tag-poll of one 32B chunk (4 tagged u64 slots) — the VERIFIED
// round-4 detect loop (incremental reload of stale slots, s_sleep backoff).
__device__ __forceinline__ float4 poll_chunk(u64* p, u32 tt) {
  u64 va = 0, vb = 0, vc = 0, vd = 0;
  bool da = false, db = false, dc = false, dd = false;
  for (;;) {
    if (!da) { va = aload(p);     da = ((u32)(va >> 32) == tt); }
    if (!db) { vb = aload(p + 1); db = ((u32)(vb >> 32) == tt); }
    if (!dc) { vc = aload(p + 2); dc = ((u32)(vc >> 32) == tt); }
    if (!dd) { vd = aload(p + 3); dd = ((u32)(vd >> 32) == tt); }
    if (__all(da && db && dc && dd)) break;
    __builtin_amdgcn_s_sleep(1);
  }
  float4 hv;
  hv.x = __uint_as_float((u32)va);
  hv.y = __uint_as_float((u32)vb);
  hv.z = __uint_as_float((u32)vc);
  hv.w = __uint_as_float((u32)vd);
  return hv;
}

// ---------------- transpose fc_w [512,1024] -> fcwT [1024,512] ----------------
__global__ void k_transpose(const float* __restrict__ w, float* __restrict__ wT) {
  int idx = blockIdx.x * 256 + threadIdx.x;   // 512*1024 total
  int k = idx >> 9;
  int o = idx & 511;
  wT[idx] = w[o * 1024 + k];
}

// ---------------- persistent recurrent kernel ----------------
// 256 blocks x 512 threads (8 waves, 1 block/CU, 2 waves/SIMD).
// Blocks 0..127: layer-0, block bx owns units 8bx..8bx+7 (one per wave).
// Blocks 128..255: layer-1, same mapping.
// Sync structure = verified round-4 scheme (serial poll, __syncthreads,
// vmcnt(0) drain after critical stores). New vs round 4:
//  - packed v_pk_fma_f32 dots (half the FMA issue count)
//  - L1 two-phase: poll h0 (arrives early; L0 runs ahead) -> cheap barrier ->
//    pre-compute Wi*h0 half while h1 is still in flight -> poll h1 ->
//    barrier -> only Wh*h1 + reduce + act + store remain post-detect.
__global__ __launch_bounds__(512)
__attribute__((amdgpu_waves_per_eu(2, 2)))
void k_recur(
    const float* __restrict__ x,
    const float* __restrict__ Whh0, const float* __restrict__ Wih0,
    const float* __restrict__ bih0, const float* __restrict__ bhh0,
    const float* __restrict__ Wih1, const float* __restrict__ Whh1,
    const float* __restrict__ bih1, const float* __restrict__ bhh1,
    const float* __restrict__ h0in, const float* __restrict__ c0in,
    u64* __restrict__ h0buf, u64* __restrict__ h1buf)
{
  __shared__ float h0s[2][LSTM_H];
  __shared__ float h1s[2][LSTM_H];   // layer-1 blocks only

  const int tid = threadIdx.x;       // 0..511
  const int w = tid >> 6, l = tid & 63;
  const bool lay1 = (blockIdx.x >= 128);
  const int bx = lay1 ? (int)blockIdx.x - 128 : (int)blockIdx.x;
  const int hd = 8 * bx + w;         // this wave's output unit

  if (!lay1) {
    // ===================== layer-0 blocks =====================
    f32x2 Wh2[4][4][2];              // Whh0 rows, packed pairs (cols q*256+4l..)
    f32x2 Wx2[4][4];                 // Wih0, cols 128m+2l..
#pragma unroll
    for (int g = 0; g < 4; ++g) {
#pragma unroll
      for (int q = 0; q < 4; ++q) {
        float4 u = *(const float4*)&Whh0[(size_t)(g * 1024 + hd) * 1024 + q * 256 + 4 * l];
        Wh2[g][q][0] = mkpair(pin1(u.x), pin1(u.y));
        Wh2[g][q][1] = mkpair(pin1(u.z), pin1(u.w));
      }
#pragma unroll
      for (int m = 0; m < 4; ++m) {
        float2 u = *(const float2*)&Wih0[(size_t)(g * 1024 + hd) * 512 + 128 * m + 2 * l];
        Wx2[g][m] = mkpair(pin1(u.x), pin1(u.y));
      }
    }
    float bsum[4];
#pragma unroll
    for (int g = 0; g < 4; ++g) bsum[g] = bih0[g * 1024 + hd] + bhh0[g * 1024 + hd];
    float c = c0in[hd];

    h0s[1][tid]       = h0in[tid];
    h0s[1][tid + 512] = h0in[tid + 512];
    __syncthreads();

    // step 0: f(h0_init, x[0]) -> h0buf slot 0, tag 0
    {
      f32x2 A0 = {0.f, 0.f}, A1 = {0.f, 0.f}, A2 = {0.f, 0.f}, A3 = {0.f, 0.f};
#pragma unroll
      for (int m = 0; m < 4; ++m) {
        f32x2 xv = *(const f32x2*)&x[128 * m + 2 * l];
        A0 = pkfma(Wx2[0][m], xv, A0);
        A1 = pkfma(Wx2[1][m], xv, A1);
        A2 = pkfma(Wx2[2][m], xv, A2);
        A3 = pkfma(Wx2[3][m], xv, A3);
      }
#pragma unroll
      for (int q = 0; q < 4; ++q) {
        float4 hq = *(const float4*)&h0s[1][q * 256 + 4 * l];
        f32x2 h01 = mkpair(hq.x, hq.y), h23 = mkpair(hq.z, hq.w);
        A0 = pkfma(Wh2[0][q][0], h01, A0); A0 = pkfma(Wh2[0][q][1], h23, A0);
        A1 = pkfma(Wh2[1][q][0], h01, A1); A1 = pkfma(Wh2[1][q][1], h23, A1);
        A2 = pkfma(Wh2[2][q][0], h01, A2); A2 = pkfma(Wh2[2][q][1], h23, A2);
        A3 = pkfma(Wh2[3][q][0], h01, A3); A3 = pkfma(Wh2[3][q][1], h23, A3);
      }
      float a0 = wsum63(A0.x + A0.y), a1 = wsum63(A1.x + A1.y);
      float a2 = wsum63(A2.x + A2.y), a3 = wsum63(A3.x + A3.y);
      c = fsig(a1 + bsum[1]) * c + fsig(a0 + bsum[0]) * ftanh(a2 + bsum[2]);
      float hn = fsig(a3 + bsum[3]) * ftanh(c);
      if (l == 63) astore(&h0buf[hd], packft(hn, 0u));   // lane 63 holds real sums
      drain_vmem();
    }

    u64* p = &h0buf[4 * tid];        // valid for tid<256 (chunk units 4tid..+3)
#pragma unroll 1
    for (int t = 0; t < LSTM_B - 1; ++t, p += 1024) {
      const int buf = t & 1;
      const u32 tt = (u32)t;
      // x(t+1) partial gates: off the critical chain, overlaps peers' flight.
      f32x2 A0 = {0.f, 0.f}, A1 = {0.f, 0.f}, A2 = {0.f, 0.f}, A3 = {0.f, 0.f};
#pragma unroll
      for (int m = 0; m < 4; ++m) {
        f32x2 xv = *(const f32x2*)&x[(size_t)(t + 1) * 512 + 128 * m + 2 * l];
        A0 = pkfma(Wx2[0][m], xv, A0);
        A1 = pkfma(Wx2[1][m], xv, A1);
        A2 = pkfma(Wx2[2][m], xv, A2);
        A3 = pkfma(Wx2[3][m], xv, A3);
      }
      // waves 0-3 poll h0(t) chunks; waves 4-7 go straight to the barrier
      if (tid < 256) {
        float4 hv = poll_chunk(p, tt);
        *(float4*)&h0s[buf][4 * tid] = hv;
      }
      __syncthreads();
#pragma unroll
      for (int q = 0; q < 4; ++q) {
        float4 hq = *(const float4*)&h0s[buf][q * 256 + 4 * l];
        f32x2 h01 = mkpair(hq.x, hq.y), h23 = mkpair(hq.z, hq.w);
        A0 = pkfma(Wh2[0][q][0], h01, A0); A0 = pkfma(Wh2[0][q][1], h23, A0);
        A1 = pkfma(Wh2[1][q][0], h01, A1); A1 = pkfma(Wh2[1][q][1], h23, A1);
        A2 = pkfma(Wh2[2][q][0], h01, A2); A2 = pkfma(Wh2[2][q][1], h23, A2);
        A3 = pkfma(Wh2[3][q][0], h01, A3); A3 = pkfma(Wh2[3][q][1], h23, A3);
      }
      float a0 = wsum63(A0.x + A0.y), a1 = wsum63(A1.x + A1.y);
      float a2 = wsum63(A2.x + A2.y), a3 = wsum63(A3.x + A3.y);
      c = fsig(a1 + bsum[1]) * c + fsig(a0 + bsum[0]) * ftanh(a2 + bsum[2]);
      float hn = fsig(a3 + bsum[3]) * ftanh(c);
      if (l == 63) astore(&h0buf[(size_t)(t + 1) * 1024 + hd], packft(hn, tt + 1));
      drain_vmem();
    }
  } else {
    // ===================== layer-1 blocks =====================
    f32x2 Wi2[4][4][2], Whh2[4][4][2];
#pragma unroll
    for (int g = 0; g < 4; ++g)
#pragma unroll
      for (int q = 0; q < 4; ++q) {
        float4 u = *(const float4*)&Wih1[(size_t)(g * 1024 + hd) * 1024 + q * 256 + 4 * l];
        Wi2[g][q][0] = mkpair(pin1(u.x), pin1(u.y));
        Wi2[g][q][1] = mkpair(pin1(u.z), pin1(u.w));
        float4 v = *(const float4*)&Whh1[(size_t)(g * 1024 + hd) * 1024 + q * 256 + 4 * l];
        Whh2[g][q][0] = mkpair(pin1(v.x), pin1(v.y));
        Whh2[g][q][1] = mkpair(pin1(v.z), pin1(v.w));
      }
    float bsum[4];
#pragma unroll
    for (int g = 0; g < 4; ++g) bsum[g] = bih1[g * 1024 + hd] + bhh1[g * 1024 + hd];
    float c = c0in[1024 + hd];
    if (l == 63) astore(&h1buf[hd], packft(h0in[1024 + hd], 0u));  // seed h1(init)
    drain_vmem();

    // split polling: threads 0-255 own h0 chunk 4*tid; 256-511 own h1 chunk
    const bool ish0 = (tid < 256);
    const int ci = ish0 ? 4 * tid : 4 * (tid - 256);
    u64* p = ish0 ? &h0buf[ci] : &h1buf[ci];
#pragma unroll 1
    for (int t = 0; t < LSTM_B; ++t, p += 1024) {
      const int buf = t & 1;
      const u32 tt = (u32)t;
      // phase 1: h0(t) — L0 runs ahead, poll passes ~immediately
      if (ish0) {
        float4 hv = poll_chunk(p, tt);
        *(float4*)&h0s[buf][ci] = hv;
      }
      __syncthreads();
      // pre-dot Wi*h0 while h1(t) is still in flight (off the critical chain)
      f32x2 A0 = {0.f, 0.f}, A1 = {0.f, 0.f}, A2 = {0.f, 0.f}, A3 = {0.f, 0.f};
#pragma unroll
      for (int q = 0; q < 4; ++q) {
        float4 hq = *(const float4*)&h0s[buf][q * 256 + 4 * l];
        f32x2 h01 = mkpair(hq.x, hq.y), h23 = mkpair(hq.z, hq.w);
        A0 = pkfma(Wi2[0][q][0], h01, A0); A0 = pkfma(Wi2[0][q][1], h23, A0);
        A1 = pkfma(Wi2[1][q][0], h01, A1); A1 = pkfma(Wi2[1][q][1], h23, A1);
        A2 = pkfma(Wi2[2][q][0], h01, A2); A2 = pkfma(Wi2[2][q][1], h23, A2);
        A3 = pkfma(Wi2[3][q][0], h01, A3); A3 = pkfma(Wi2[3][q][1], h23, A3);
      }
      // phase 2: h1(t) — the rate-setting detect
      if (!ish0) {
        float4 hv = poll_chunk(p, tt);
        *(float4*)&h1s[buf][ci] = hv;
      }
      __syncthreads();
#pragma unroll
      for (int q = 0; q < 4; ++q) {
        float4 hq = *(const float4*)&h1s[buf][q * 256 + 4 * l];
        f32x2 h01 = mkpair(hq.x, hq.y), h23 = mkpair(hq.z, hq.w);
        A0 = pkfma(Whh2[0][q][0], h01, A0); A0 = pkfma(Whh2[0][q][1], h23, A0);
        A1 = pkfma(Whh2[1][q][0], h01, A1); A1 = pkfma(Whh2[1][q][1], h23, A1);
        A2 = pkfma(Whh2[2][q][0], h01, A2); A2 = pkfma(Whh2[2][q][1], h23, A2);
        A3 = pkfma(Whh2[3][q][0], h01, A3); A3 = pkfma(Whh2[3][q][1], h23, A3);
      }
      float a0 = wsum63(A0.x + A0.y), a1 = wsum63(A1.x + A1.y);
      float a2 = wsum63(A2.x + A2.y), a3 = wsum63(A3.x + A3.y);
      c = fsig(a1 + bsum[1]) * c + fsig(a0 + bsum[0]) * ftanh(a2 + bsum[2]);
      float hn = fsig(a3 + bsum[3]) * ftanh(c);
      if (l == 63) astore(&h1buf[(size_t)(t + 1) * 1024 + hd], packft(hn, tt + 1));
      drain_vmem();
    }
  }
}

// ---------------- FC + softmax: 16 timesteps per block ----------------
__global__ __launch_bounds__(256) void k_fc(u64* __restrict__ h1buf,
                                            const float* __restrict__ fcwT,
                                            const float* __restrict__ fcb,
                                            float* __restrict__ out) {
  __shared__ float smem[16 * 1024];
  const int tid = threadIdx.x;
  const int t0 = blockIdx.x * 16;

  for (int i = 0; i < 64; ++i) {
    int e = tid + 256 * i;
    int tt = e >> 10, k = e & 1023;
    u64 v = aload(&h1buf[(size_t)(t0 + tt + 1) * 1024 + k]);
    smem[e] = __uint_as_float((u32)v);
  }
  __syncthreads();

  float acc0[16], acc1[16];
#pragma unroll
  for (int tt = 0; tt < 16; ++tt) { acc0[tt] = 0.f; acc1[tt] = 0.f; }

  for (int k0 = 0; k0 < 1024; k0 += 4) {
    float4 w0v, w1v;
    w0v.x = fcwT[(k0 + 0) * 512 + tid];       w1v.x = fcwT[(k0 + 0) * 512 + 256 + tid];
    w0v.y = fcwT[(k0 + 1) * 512 + tid];       w1v.y = fcwT[(k0 + 1) * 512 + 256 + tid];
    w0v.z = fcwT[(k0 + 2) * 512 + tid];       w1v.z = fcwT[(k0 + 2) * 512 + 256 + tid];
    w0v.w = fcwT[(k0 + 3) * 512 + tid];       w1v.w = fcwT[(k0 + 3) * 512 + 256 + tid];
    float4 hv[16];
#pragma unroll
    for (int tt = 0; tt < 16; ++tt) hv[tt] = *(const float4*)&smem[tt * 1024 + k0];
#pragma unroll
    for (int tt = 0; tt < 16; ++tt) {
      acc0[tt] += dot4f(w0v, hv[tt]);
      acc1[tt] += dot4f(w1v, hv[tt]);
    }
  }
  float bb0 = fcb[tid], bb1 = fcb[tid + 256];
  __syncthreads();  // done reading h1 tile; alias smem as logits [16][512]
#pragma unroll
  for (int tt = 0; tt < 16; ++tt) {
    smem[tt * 512 + tid] = acc0[tt] + bb0;
    smem[tt * 512 + 256 + tid] = acc1[tt] + bb1;
  }
  __syncthreads();

  const int wv = tid >> 6, l = tid & 63;
  for (int r = 0; r < 4; ++r) {
    int tt = wv * 4 + r;
    float v[8];
    float mx = -3.4e38f;
#pragma unroll
    for (int m = 0; m < 8; ++m) { v[m] = smem[tt * 512 + m * 64 + l]; mx = fmaxf(mx, v[m]); }
#pragma unroll
    for (int s = 1; s < 64; s <<= 1) mx = fmaxf(mx, __shfl_xor(mx, s, 64));
    float sum = 0.f;
#pragma unroll
    for (int m = 0; m < 8; ++m) { v[m] = expf(v[m] - mx); sum += v[m]; }
#pragma unroll
    for (int s = 1; s < 64; s <<= 1) sum += __shfl_xor(sum, s, 64);
    float inv = 1.0f / sum;
#pragma unroll
    for (int m = 0; m < 8; ++m) out[(size_t)(t0 + tt) * 512 + m * 64 + l] = v[m] * inv;
  }
}

extern "C" void kernel_launch(void* const* d_in, const int* in_sizes, int n_in,
                              void* d_out, int out_size, void* d_ws, size_t ws_size,
                              hipStream_t stream) {
  const float* x    = (const float*)d_in[0];
  const float* Wih0 = (const float*)d_in[1];
  const float* Whh0 = (const float*)d_in[2];
  const float* bih0 = (const float*)d_in[3];
  const float* bhh0 = (const float*)d_in[4];
  const float* Wih1 = (const float*)d_in[5];
  const float* Whh1 = (const float*)d_in[6];
  const float* bih1 = (const float*)d_in[7];
  const float* bhh1 = (const float*)d_in[8];
  const float* h0in = (const float*)d_in[9];
  const float* c0in = (const float*)d_in[10];
  const float* fcw  = (const float*)d_in[11];
  const float* fcb  = (const float*)d_in[12];
  float* out = (float*)d_out;

  // workspace: h0buf (B slots) | h1buf (B+1 slots) | fcwT  -> ~69 MB
  u64* h0buf = (u64*)d_ws;
  u64* h1buf = h0buf + (size_t)LSTM_B * 1024;
  float* fcwT = (float*)(h1buf + (size_t)(LSTM_B + 1) * 1024);

  hipLaunchKernelGGL(k_transpose, dim3((512 * 1024) / 256), dim3(256), 0, stream, fcw, fcwT);
  hipLaunchKernelGGL(k_recur, dim3(256), dim3(512), 0, stream,
                     x, Whh0, Wih0, bih0, bhh0, Wih1, Whh1, bih1, bhh1,
                     h0in, c0in, h0buf, h1buf);
  hipLaunchKernelGGL(k_fc, dim3(LSTM_B / 16), dim3(256), 0, stream, h1buf, fcwT, fcb, out);
}